// Round 5
// baseline (448.380 us; speedup 1.0000x reference)
//
#include <hip/hip_runtime.h>

// ---- sizes ----
// x: (1024,1,28,28); h1: (1024,32,14,14); h2: (1024,64,14,14)->12544; out: (1024,10)
#define NB 1024
#define TOTAL1 (NB*196)

// ws layout (float offsets)
#define WS_H1   0               // 1024*32*196      = 6422528
#define WS_H2   6422528         // 1024*12544      = 12845056
#define WS_PART 19267584        // 32*1024*128     = 4194304
#define WS_OFF2 WS_PART         // off2[1024][18][196]; dead before fc1 writes partials
#define WS_W1T  23461888        // 288
#define WS_OW1T 23462176        // 162
#define WS_W2T  23462338        // 18432  [k=ci*9+kk][co=64]
#define WS_OW2T 23480770        // 5184   [k=ci*9+j][c=18]

// ---------------- weight transpose prep ----------------
__global__ __launch_bounds__(256) void prep(const float* __restrict__ w1,
                                            const float* __restrict__ ow1,
                                            const float* __restrict__ w2,
                                            const float* __restrict__ ow2,
                                            float* __restrict__ ws) {
  int i = blockIdx.x * 256 + threadIdx.x;
  if (i < 288)   { int co = i / 9,  kk = i % 9;   ws[WS_W1T  + kk * 32 + co] = w1[i]; }
  if (i < 162)   { int c  = i / 9,  j  = i % 9;   ws[WS_OW1T + j  * 18 + c ] = ow1[i]; }
  if (i < 18432) { int co = i / 288, k = i % 288; ws[WS_W2T  + k  * 64 + co] = w2[i]; }
  if (i < 5184)  { int c  = i / 288, k = i % 288; ws[WS_OW2T + k  * 18 + c ] = ow2[i]; }
}

// ---------------- stage 1: offset conv + deform conv (1->32) + relu + pool 28->14 ----------------
__global__ __launch_bounds__(256, 2) void stage1(const float* __restrict__ x,
                                                 const float* __restrict__ ob1,
                                                 const float* __restrict__ b1,
                                                 const float* __restrict__ ws,
                                                 float* __restrict__ h1) {
  __shared__ float ximg[3 * 784];
  const float* __restrict__ w1t  = ws + WS_W1T;   // [kk][32]
  const float* __restrict__ ow1t = ws + WS_OW1T;  // [j][18]
  int tid = threadIdx.x;
  int g0 = blockIdx.x * 256;
  int bfirst = g0 / 196;
  for (int idx = tid; idx < 3 * 784; idx += 256) {
    int img = idx / 784;
    int b = bfirst + img;
    ximg[idx] = (b < NB) ? x[b * 784 + (idx - img * 784)] : 0.f;
  }
  __syncthreads();
  int g = g0 + tid;
  if (g >= TOTAL1) return;
  int b = g / 196, p = g - b * 196;
  const float* im = ximg + (b - bfirst) * 784;
  int oy = p / 14, ox = p - (p / 14) * 14;

  float pooled[32];
#pragma unroll
  for (int co = 0; co < 32; ++co) pooled[co] = 0.f;

  for (int sub = 0; sub < 4; ++sub) {
    int y  = 2 * oy + (sub >> 1);
    int ix = 2 * ox + (sub & 1);
    float patch[9];
#pragma unroll
    for (int j = 0; j < 9; ++j) {
      int yy = y + j / 3 - 1, xc = ix + j % 3 - 1;
      bool ok = (yy >= 0) & (yy < 28) & (xc >= 0) & (xc < 28);
      patch[j] = ok ? im[yy * 28 + xc] : 0.f;
    }
    float off[18];
#pragma unroll
    for (int c = 0; c < 18; ++c) off[c] = ob1[c];
#pragma unroll
    for (int j = 0; j < 9; ++j) {
      float v = patch[j];
#pragma unroll
      for (int c = 0; c < 18; ++c) off[c] = fmaf(v, ow1t[j * 18 + c], off[c]);
    }
    float a[32];
#pragma unroll
    for (int co = 0; co < 32; ++co) a[co] = b1[co];
#pragma unroll
    for (int kk = 0; kk < 9; ++kk) {
      float py = (float)(y - 1 + kk / 3) + off[2 * kk];
      float px = (float)(ix - 1 + kk % 3) + off[2 * kk + 1];
      float y0f = floorf(py), x0f = floorf(px);
      float wy1 = py - y0f, wx1 = px - x0f;
      float wy0 = 1.f - wy1, wx0 = 1.f - wx1;
      int y0 = (int)y0f, x0 = (int)x0f;
      int y1 = y0 + 1, x1 = x0 + 1;
      bool vy0 = (y0 >= 0) & (y0 < 28), vy1 = (y1 >= 0) & (y1 < 28);
      bool vx0 = (x0 >= 0) & (x0 < 28), vx1 = (x1 >= 0) & (x1 < 28);
      float W00 = (vy0 & vx0) ? wy0 * wx0 : 0.f;
      float W01 = (vy0 & vx1) ? wy0 * wx1 : 0.f;
      float W10 = (vy1 & vx0) ? wy1 * wx0 : 0.f;
      float W11 = (vy1 & vx1) ? wy1 * wx1 : 0.f;
      int yc0 = min(max(y0, 0), 27), yc1 = min(max(y1, 0), 27);
      int xc0 = min(max(x0, 0), 27), xc1 = min(max(x1, 0), 27);
      float s = im[yc0 * 28 + xc0] * W00 + im[yc0 * 28 + xc1] * W01 +
                im[yc1 * 28 + xc0] * W10 + im[yc1 * 28 + xc1] * W11;
#pragma unroll
      for (int co = 0; co < 32; ++co) a[co] = fmaf(s, w1t[kk * 32 + co], a[co]);
    }
#pragma unroll
    for (int co = 0; co < 32; ++co) pooled[co] += fmaxf(a[co], 0.f);
  }
#pragma unroll
  for (int co = 0; co < 32; ++co) h1[b * 6272 + co * 196 + p] = pooled[co] * 0.25f;
}

// ---------------- offconv v2: thread-per-pixel in-register offset conv (32->18) ----------------
// Block = 448 threads = 2 images x 224 slots (14x16; cols 14,15 duplicate col 13, stores guarded).
// No Sbuf, one barrier. Weights wave-uniform -> s_load. Stores coalesced ([b][18][196], lane=p).
// This exact in-register structure compiled spill-free at 64 VGPR in v7 (spill there was acc[64]).
__global__ __launch_bounds__(448, 4) void offconv(const float* __restrict__ h1,
                                                  const float* __restrict__ ob2,
                                                  const float* __restrict__ ws,
                                                  float* __restrict__ off2) {
  __shared__ float imgT[2 * 6272];       // imgT[img][p*32 + ((ci+4p)&31)] = img[ci][p]
  const float* __restrict__ ow2t = ws + WS_OW2T;  // [ci*9+j][18]
  int tid = threadIdx.x;
  int bb = blockIdx.x;  // images 2bb, 2bb+1

  for (int e = tid; e < 12544; e += 448) {
    int img = e / 6272, rem = e - img * 6272;
    int ci = rem / 196, p = rem - ci * 196;
    imgT[img * 6272 + p * 32 + ((ci + 4 * p) & 31)] = h1[bb * 12544 + e];
  }
  __syncthreads();

  int img  = tid / 224;
  int slot = tid - img * 224;
  int py  = slot >> 4;        // 0..13
  int pxc = slot & 15;        // 0..15 (14,15 = pad)
  int pxx = min(pxc, 13);
  int p   = py * 14 + pxx;
  const float* im = imgT + img * 6272;

  float off[18];
#pragma unroll
  for (int c = 0; c < 18; ++c) off[c] = ob2[c];
  for (int j = 0; j < 9; ++j) {
    int yy = py + j / 3 - 1, xx = pxx + j % 3 - 1;
    bool ok = (yy >= 0) & (yy < 14) & (xx >= 0) & (xx < 14);
    int nidx = ok ? (yy * 14 + xx) : 0;
    const float* src = im + nidx * 32;
    int rot = (4 * nidx) & 31;
    for (int cq = 0; cq < 8; ++cq) {
      float4 v;
      if (ok) v = *(const float4*)(src + ((cq * 4 + rot) & 31));
      else    v = make_float4(0.f, 0.f, 0.f, 0.f);
      const float* w0 = ow2t + ((cq * 4 + 0) * 9 + j) * 18;
      const float* w1 = ow2t + ((cq * 4 + 1) * 9 + j) * 18;
      const float* w2 = ow2t + ((cq * 4 + 2) * 9 + j) * 18;
      const float* w3 = ow2t + ((cq * 4 + 3) * 9 + j) * 18;
#pragma unroll
      for (int c = 0; c < 18; ++c) {
        off[c] = fmaf(v.x, w0[c], off[c]);
        off[c] = fmaf(v.y, w1[c], off[c]);
        off[c] = fmaf(v.z, w2[c], off[c]);
        off[c] = fmaf(v.w, w3[c], off[c]);
      }
    }
  }

  if (pxc < 14) {
    float* dst = off2 + (2 * bb + img) * 3528 + p;
#pragma unroll
    for (int c = 0; c < 18; ++c) dst[c * 196] = off[c];
  }
}

// ---------------- stage 2 v6 (verbatim from R2, measured 177us): pipelined sample||GEMM ----------------
// LDS: imgT 25088B + Sbuf2 12864B = 37952B -> 4 blocks/CU, no tail.
// Offsets precomputed by offconv (global, L2). Per interval t=kk*4+q:
//   sample quarter (q+1) of its tap into buf[(q+1)&1]  ||  GEMM quarter q of tap kk from buf[q&1]
__global__ __launch_bounds__(256, 4) void stage2(const float* __restrict__ h1,
                                                 const float* __restrict__ off2,
                                                 const float* __restrict__ b2,
                                                 const float* __restrict__ ws,
                                                 float* __restrict__ h2) {
  __shared__ float imgT[196 * 32];       // imgT[p*32 + ((ci+4p)&31)] = img[ci][p]
  __shared__ float Sbuf2[2 * 1608];      // two quarter-buffers: 8 rows x 200 + 8 guard each
  const float* __restrict__ w2t = ws + WS_W2T;
  int tid = threadIdx.x;
  int b = blockIdx.x;

  // ---- phase 1: load image, transposed + bank-rotated ----
  for (int e = tid; e < 6272; e += 256) {
    int ci = e / 196, p = e - ci * 196;
    imgT[p * 32 + ((ci + 4 * p) & 31)] = h1[b * 6272 + e];
  }

  // sampler identity
  int pp = tid;
  int spy = pp / 14, spx = pp - (pp / 14) * 14;
  bool samp = (pp < 196);
  const float* off_b = off2 + b * 3528;

  // GEMM identity: 16 cog x 13 pg (208 threads)
  int cog = tid & 15, pg = tid >> 4;
  int co0 = cog * 4, p0 = pg * 16;
  bool gact = (pg < 13);
  float acc[4][16];
  {
    float4 bb = *(const float4*)(b2 + co0);
    float bj[4] = {bb.x, bb.y, bb.z, bb.w};
#pragma unroll
    for (int jj = 0; jj < 4; ++jj)
#pragma unroll
      for (int i = 0; i < 16; ++i) acc[jj][i] = bj[jj];
  }

  // persistent sampler state (one tap's bilinear coeffs, reused across its 4 quarters)
  float W00 = 0.f, W01 = 0.f, W10 = 0.f, W11 = 0.f;
  int s00o = 0, s01o = 0, s10o = 0, s11o = 0;
  int r00 = 0, r01 = 0, r10 = 0, r11 = 0;
  float dyn = 0.f, dxn = 0.f;  // prefetched offsets for the NEXT tap

  auto coeff = [&](int kkv) {
    float pyv = (float)(spy - 1 + kkv / 3) + dyn;
    float pxv = (float)(spx - 1 + kkv % 3) + dxn;
    float y0f = floorf(pyv), x0f = floorf(pxv);
    float wy1 = pyv - y0f, wx1 = pxv - x0f;
    float wy0 = 1.f - wy1, wx0 = 1.f - wx1;
    int y0 = (int)y0f, x0 = (int)x0f;
    int y1 = y0 + 1, x1 = x0 + 1;
    bool vy0 = (y0 >= 0) & (y0 < 14), vy1 = (y1 >= 0) & (y1 < 14);
    bool vx0 = (x0 >= 0) & (x0 < 14), vx1 = (x1 >= 0) & (x1 < 14);
    W00 = (vy0 & vx0) ? wy0 * wx0 : 0.f;
    W01 = (vy0 & vx1) ? wy0 * wx1 : 0.f;
    W10 = (vy1 & vx0) ? wy1 * wx0 : 0.f;
    W11 = (vy1 & vx1) ? wy1 * wx1 : 0.f;
    int yc0 = min(max(y0, 0), 13), yc1 = min(max(y1, 0), 13);
    int xc0 = min(max(x0, 0), 13), xc1 = min(max(x1, 0), 13);
    int i00 = yc0 * 14 + xc0, i01 = yc0 * 14 + xc1;
    int i10 = yc1 * 14 + xc0, i11 = yc1 * 14 + xc1;
    s00o = i00 * 32; r00 = (4 * i00) & 31;
    s01o = i01 * 32; r01 = (4 * i01) & 31;
    s10o = i10 * 32; r10 = (4 * i10) & 31;
    s11o = i11 * 32; r11 = (4 * i11) & 31;
  };

  auto sample = [&](int qn, int bufn) {
    float* dst = Sbuf2 + bufn * 1608 + pp;
#pragma unroll
    for (int cg = 0; cg < 2; ++cg) {
      int gq = qn * 2 + cg;  // global channel quad
      float4 a0 = *(const float4*)(imgT + s00o + ((gq * 4 + r00) & 31));
      float4 a1 = *(const float4*)(imgT + s01o + ((gq * 4 + r01) & 31));
      float4 a2 = *(const float4*)(imgT + s10o + ((gq * 4 + r10) & 31));
      float4 a3 = *(const float4*)(imgT + s11o + ((gq * 4 + r11) & 31));
      dst[(cg * 4 + 0) * 200] = fmaf(W00, a0.x, fmaf(W01, a1.x, fmaf(W10, a2.x, W11 * a3.x)));
      dst[(cg * 4 + 1) * 200] = fmaf(W00, a0.y, fmaf(W01, a1.y, fmaf(W10, a2.y, W11 * a3.y)));
      dst[(cg * 4 + 2) * 200] = fmaf(W00, a0.z, fmaf(W01, a1.z, fmaf(W10, a2.z, W11 * a3.z)));
      dst[(cg * 4 + 3) * 200] = fmaf(W00, a0.w, fmaf(W01, a1.w, fmaf(W10, a2.w, W11 * a3.w)));
    }
  };

  // prologue: tap 0 coeffs + sample quarter 0 into buf 0
  if (samp) { dyn = off_b[pp]; dxn = off_b[196 + pp]; }
  __syncthreads();  // imgT ready
  if (samp) { coeff(0); sample(0, 0); }
  __syncthreads();  // buf0 quarter 0 ready

  for (int kk = 0; kk < 9; ++kk) {
#pragma unroll
    for (int q = 0; q < 4; ++q) {
      // ---- sample quarter for NEXT interval ----
      if (samp && !((kk == 8) & (q == 3))) {
        if (q == 1 && kk < 8) {
          dyn = off_b[(2 * kk + 2) * 196 + pp];
          dxn = off_b[(2 * kk + 3) * 196 + pp];
        }
        if (q == 3) coeff(kk + 1);  // next tap's coeffs (this tap's quarters all sampled)
        sample((q + 1) & 3, (q + 1) & 1);
      }
      // ---- GEMM current quarter ----
      if (gact) {
        const float* sb = Sbuf2 + (q & 1) * 1608 + p0;
        const float* wb = w2t + kk * 64 + co0;
#pragma unroll 2
        for (int l = 0; l < 8; ++l) {
          int ci = q * 8 + l;
          float4 w = *(const float4*)(wb + ci * 576);
          const float* srow = sb + l * 200;
          float4 s0 = *(const float4*)(srow);
          float4 s1 = *(const float4*)(srow + 4);
          float4 s2 = *(const float4*)(srow + 8);
          float4 s3 = *(const float4*)(srow + 12);
          float sv[16] = {s0.x, s0.y, s0.z, s0.w, s1.x, s1.y, s1.z, s1.w,
                          s2.x, s2.y, s2.z, s2.w, s3.x, s3.y, s3.z, s3.w};
          float wj[4] = {w.x, w.y, w.z, w.w};
#pragma unroll
          for (int jj = 0; jj < 4; ++jj)
#pragma unroll
            for (int i = 0; i < 16; ++i)
              acc[jj][i] = fmaf(wj[jj], sv[i], acc[jj][i]);
        }
      }
      __syncthreads();
    }
  }

  // ---- epilogue: ReLU + direct float4 global stores ----
  if (gact) {
    float* __restrict__ orow = h2 + b * 12544 + co0 * 196 + p0;
#pragma unroll
    for (int jj = 0; jj < 4; ++jj) {
#pragma unroll
      for (int t = 0; t < 4; ++t) {
        if (p0 + 4 * t < 196) {
          float4 v;
          v.x = fmaxf(acc[jj][4 * t + 0], 0.f);
          v.y = fmaxf(acc[jj][4 * t + 1], 0.f);
          v.z = fmaxf(acc[jj][4 * t + 2], 0.f);
          v.w = fmaxf(acc[jj][4 * t + 3], 0.f);
          *(float4*)(orow + jj * 196 + 4 * t) = v;
        }
      }
    }
  }
}

// ---------------- fc1: K-split GEMM 1024x128, K=12544 -> partials[32][1024][128] ----------------
__global__ __launch_bounds__(256, 2) void fc1(const float* __restrict__ h2,
                                              const float* __restrict__ fw1,
                                              float* __restrict__ part) {
  __shared__ float a_s[56 * 72];   // [k][r]
  __shared__ float b_s[56 * 132];  // [k][c]
  int tid = threadIdx.x;
  int rb = (blockIdx.x & 15) * 64;
  int ks = blockIdx.x >> 4;
  int kbase = ks * 392;
  int c0 = (tid & 31) * 4;
  int r0 = (tid >> 5) * 8;

  float acc[8][4];
#pragma unroll
  for (int i = 0; i < 8; ++i)
#pragma unroll
    for (int j = 0; j < 4; ++j) acc[i][j] = 0.f;

  for (int ch = 0; ch < 7; ++ch) {
    int kb = kbase + ch * 56;
    __syncthreads();
#pragma unroll
    for (int t = 0; t < 14; ++t) {
      int idx = t * 256 + tid;
      int r = idx / 56, k = idx - r * 56;
      a_s[k * 72 + r] = h2[(rb + r) * 12544 + kb + k];
    }
#pragma unroll
    for (int t = 0; t < 28; ++t) {
      int idx = t * 256 + tid;
      int c = idx / 56, k = idx - c * 56;
      b_s[k * 132 + c] = fw1[c * 12544 + kb + k];
    }
    __syncthreads();
    for (int k = 0; k < 56; ++k) {
      float4 bv = *(const float4*)&b_s[k * 132 + c0];
      float4 av0 = *(const float4*)&a_s[k * 72 + r0];
      float4 av1 = *(const float4*)&a_s[k * 72 + r0 + 4];
      float av[8] = {av0.x, av0.y, av0.z, av0.w, av1.x, av1.y, av1.z, av1.w};
      float bj[4] = {bv.x, bv.y, bv.z, bv.w};
#pragma unroll
      for (int i = 0; i < 8; ++i)
#pragma unroll
        for (int j = 0; j < 4; ++j) acc[i][j] = fmaf(av[i], bj[j], acc[i][j]);
    }
  }
#pragma unroll
  for (int i = 0; i < 8; ++i) {
    int r = rb + r0 + i;
#pragma unroll
    for (int j = 0; j < 4; ++j)
      part[(ks * 1024 + r) * 128 + c0 + j] = acc[i][j];
  }
}

// ---------------- reduce partials + bias + relu + fc2 ----------------
__global__ __launch_bounds__(128) void fcfinal(const float* __restrict__ part,
                                               const float* __restrict__ fb1,
                                               const float* __restrict__ fw2,
                                               const float* __restrict__ fb2,
                                               float* __restrict__ out) {
  __shared__ float tbuf[128];
  int b = blockIdx.x, c = threadIdx.x;
  float s = fb1[c];
  for (int ks = 0; ks < 32; ++ks) s += part[(ks * 1024 + b) * 128 + c];
  tbuf[c] = fmaxf(s, 0.f);
  __syncthreads();
  if (c < 10) {
    float v = fb2[c];
#pragma unroll
    for (int k = 0; k < 128; ++k) v = fmaf(tbuf[k], fw2[c * 128 + k], v);
    out[b * 10 + c] = v;
  }
}

extern "C" void kernel_launch(void* const* d_in, const int* in_sizes, int n_in,
                              void* d_out, int out_size, void* d_ws, size_t ws_size,
                              hipStream_t stream) {
  const float* x   = (const float*)d_in[0];
  const float* ow1 = (const float*)d_in[1];
  const float* ob1 = (const float*)d_in[2];
  const float* w1  = (const float*)d_in[3];
  const float* b1  = (const float*)d_in[4];
  const float* ow2 = (const float*)d_in[5];
  const float* ob2 = (const float*)d_in[6];
  const float* w2  = (const float*)d_in[7];
  const float* b2  = (const float*)d_in[8];
  const float* fw1 = (const float*)d_in[9];
  const float* fb1 = (const float*)d_in[10];
  const float* fw2 = (const float*)d_in[11];
  const float* fb2 = (const float*)d_in[12];
  float* ws  = (float*)d_ws;
  float* out = (float*)d_out;

  prep<<<72, 256, 0, stream>>>(w1, ow1, w2, ow2, ws);
  stage1<<<784, 256, 0, stream>>>(x, ob1, b1, ws, ws + WS_H1);
  offconv<<<512, 448, 0, stream>>>(ws + WS_H1, ob2, ws, ws + WS_OFF2);
  stage2<<<NB, 256, 0, stream>>>(ws + WS_H1, ws + WS_OFF2, b2, ws, ws + WS_H2);
  fc1<<<512, 256, 0, stream>>>(ws + WS_H2, fw1, ws + WS_PART);
  fcfinal<<<1024, 128, 0, stream>>>(ws + WS_PART, fb1, fw2, fb2, out);
}

// Round 6
// 403.892 us; speedup vs baseline: 1.1101x; 1.1101x over previous
//
#include <hip/hip_runtime.h>

// ---- sizes ----
// x: (1024,1,28,28); h1: (1024,32,14,14); h2: (1024,64,14,14)->12544; out: (1024,10)
#define NB 1024
#define TOTAL1 (NB*196)

// ws layout (float offsets)
#define WS_H1   0               // 1024*32*196      = 6422528
#define WS_H2   6422528         // 1024*12544      = 12845056
#define WS_PART 19267584        // 32*1024*128     = 4194304
#define WS_W1T  23461888        // 288
#define WS_OW1T 23462176        // 162
#define WS_W2T  23462338        // 18432  [k=ci*9+kk][co=64]
#define WS_OW2T 23480770        // 5184   [k=ci*9+j][c=18]

// ---------------- weight transpose prep ----------------
__global__ __launch_bounds__(256) void prep(const float* __restrict__ w1,
                                            const float* __restrict__ ow1,
                                            const float* __restrict__ w2,
                                            const float* __restrict__ ow2,
                                            float* __restrict__ ws) {
  int i = blockIdx.x * 256 + threadIdx.x;
  if (i < 288)   { int co = i / 9,  kk = i % 9;   ws[WS_W1T  + kk * 32 + co] = w1[i]; }
  if (i < 162)   { int c  = i / 9,  j  = i % 9;   ws[WS_OW1T + j  * 18 + c ] = ow1[i]; }
  if (i < 18432) { int co = i / 288, k = i % 288; ws[WS_W2T  + k  * 64 + co] = w2[i]; }
  if (i < 5184)  { int c  = i / 288, k = i % 288; ws[WS_OW2T + k  * 18 + c ] = ow2[i]; }
}

// ---------------- stage 1: offset conv + deform conv (1->32) + relu + pool 28->14 ----------------
__global__ __launch_bounds__(256, 2) void stage1(const float* __restrict__ x,
                                                 const float* __restrict__ ob1,
                                                 const float* __restrict__ b1,
                                                 const float* __restrict__ ws,
                                                 float* __restrict__ h1) {
  __shared__ float ximg[3 * 784];
  const float* __restrict__ w1t  = ws + WS_W1T;   // [kk][32]
  const float* __restrict__ ow1t = ws + WS_OW1T;  // [j][18]
  int tid = threadIdx.x;
  int g0 = blockIdx.x * 256;
  int bfirst = g0 / 196;
  for (int idx = tid; idx < 3 * 784; idx += 256) {
    int img = idx / 784;
    int b = bfirst + img;
    ximg[idx] = (b < NB) ? x[b * 784 + (idx - img * 784)] : 0.f;
  }
  __syncthreads();
  int g = g0 + tid;
  if (g >= TOTAL1) return;
  int b = g / 196, p = g - b * 196;
  const float* im = ximg + (b - bfirst) * 784;
  int oy = p / 14, ox = p - (p / 14) * 14;

  float pooled[32];
#pragma unroll
  for (int co = 0; co < 32; ++co) pooled[co] = 0.f;

  for (int sub = 0; sub < 4; ++sub) {
    int y  = 2 * oy + (sub >> 1);
    int ix = 2 * ox + (sub & 1);
    float patch[9];
#pragma unroll
    for (int j = 0; j < 9; ++j) {
      int yy = y + j / 3 - 1, xc = ix + j % 3 - 1;
      bool ok = (yy >= 0) & (yy < 28) & (xc >= 0) & (xc < 28);
      patch[j] = ok ? im[yy * 28 + xc] : 0.f;
    }
    float off[18];
#pragma unroll
    for (int c = 0; c < 18; ++c) off[c] = ob1[c];
#pragma unroll
    for (int j = 0; j < 9; ++j) {
      float v = patch[j];
#pragma unroll
      for (int c = 0; c < 18; ++c) off[c] = fmaf(v, ow1t[j * 18 + c], off[c]);
    }
    float a[32];
#pragma unroll
    for (int co = 0; co < 32; ++co) a[co] = b1[co];
#pragma unroll
    for (int kk = 0; kk < 9; ++kk) {
      float py = (float)(y - 1 + kk / 3) + off[2 * kk];
      float px = (float)(ix - 1 + kk % 3) + off[2 * kk + 1];
      float y0f = floorf(py), x0f = floorf(px);
      float wy1 = py - y0f, wx1 = px - x0f;
      float wy0 = 1.f - wy1, wx0 = 1.f - wx1;
      int y0 = (int)y0f, x0 = (int)x0f;
      int y1 = y0 + 1, x1 = x0 + 1;
      bool vy0 = (y0 >= 0) & (y0 < 28), vy1 = (y1 >= 0) & (y1 < 28);
      bool vx0 = (x0 >= 0) & (x0 < 28), vx1 = (x1 >= 0) & (x1 < 28);
      float W00 = (vy0 & vx0) ? wy0 * wx0 : 0.f;
      float W01 = (vy0 & vx1) ? wy0 * wx1 : 0.f;
      float W10 = (vy1 & vx0) ? wy1 * wx0 : 0.f;
      float W11 = (vy1 & vx1) ? wy1 * wx1 : 0.f;
      int yc0 = min(max(y0, 0), 27), yc1 = min(max(y1, 0), 27);
      int xc0 = min(max(x0, 0), 27), xc1 = min(max(x1, 0), 27);
      float s = im[yc0 * 28 + xc0] * W00 + im[yc0 * 28 + xc1] * W01 +
                im[yc1 * 28 + xc0] * W10 + im[yc1 * 28 + xc1] * W11;
#pragma unroll
      for (int co = 0; co < 32; ++co) a[co] = fmaf(s, w1t[kk * 32 + co], a[co]);
    }
#pragma unroll
    for (int co = 0; co < 32; ++co) pooled[co] += fmaxf(a[co], 0.f);
  }
#pragma unroll
  for (int co = 0; co < 32; ++co) h1[b * 6272 + co * 196 + p] = pooled[co] * 0.25f;
}

// ---------------- stage 2 v9: fully fused, both phases quarter-pipelined ----------------
// LDS: imgT 25088 + Sbuf2 12864 + offT 1664 = 39616B -> 4 blocks/CU, no tail.
// Phase 2 (offset conv 32->18): interval (j,q) = {int-shift sample quarter q+1 || oGEMM quarter q}.
//   oGEMM mapping (v4, amortizes weights 16x): oc=tid%18, opg=tid/18, oacc[16].
// offT publish: tap kk's (dy,dx) written by owning oacc threads at interval (kk-1,q=2),
//   consumed by sampler coeff at (kk-1,q=3); interval barrier provides ordering.
// Phase 3 (deform conv 32->64): v6 schedule, GEMM remapped to 8co x 8px (cog=tid&7,pg=tid>>3):
//   8 lanes/wave read the SAME Sbuf address (LDS broadcast) -> GEMM b128 reads halve (32->16).
__global__ __launch_bounds__(256, 4) void stage2(const float* __restrict__ h1,
                                                 const float* __restrict__ ob2,
                                                 const float* __restrict__ b2,
                                                 const float* __restrict__ ws,
                                                 float* __restrict__ h2) {
  __shared__ float imgT[196 * 32];       // imgT[p*32 + ((ci+4p)&31)] = img[ci][p]
  __shared__ float Sbuf2[2 * 1608];      // two quarter-buffers: 8 rows x 200 + 8 guard each
  __shared__ float offT[2 * 208];        // current tap's (dy,dx)
  const float* __restrict__ w2t  = ws + WS_W2T;   // [ci*9+kk][co=64]
  const float* __restrict__ ow2t = ws + WS_OW2T;  // [ci*9+j][c=18]
  int tid = threadIdx.x;
  int b = blockIdx.x;

  // ---- phase 1: load image, transposed + bank-rotated ----
  for (int e = tid; e < 6272; e += 256) {
    int ci = e / 196, p = e - ci * 196;
    imgT[p * 32 + ((ci + 4 * p) & 31)] = h1[b * 6272 + e];
  }

  // sampler identity
  int pp = tid;
  int spy = pp / 14, spx = pp - (pp / 14) * 14;
  bool samp = (pp < 196);

  // phase-2 oGEMM identity: 18 oc x 13 groups of 16 px = 234 threads
  int oc  = tid % 18;
  int opg = tid / 18;
  int op0 = opg * 16;
  bool oact = (tid < 234);
  float myob = oact ? ob2[oc] : 0.f;
  float oacc[16];
#pragma unroll
  for (int i = 0; i < 16; ++i) oacc[i] = 0.f;

  // phase-3 GEMM identity: 8 cog x 25 groups of 8 px = 200 threads
  int cog = tid & 7, pg = tid >> 3;
  int co0 = cog * 8, p0 = pg * 8;
  bool gact = (pg < 25);

  // ---- phase-2 sampler: integer-shift quarter into Sbuf2 ----
  auto p2sample = [&](int j, int qn, int bufn) {
    int yy = spy + j / 3 - 1, xx = spx + j % 3 - 1;
    bool ok = (yy >= 0) & (yy < 14) & (xx >= 0) & (xx < 14);
    int nidx = ok ? (yy * 14 + xx) : 0;
    const float* src = imgT + nidx * 32;
    int rot = (4 * nidx) & 31;
    float* dst = Sbuf2 + bufn * 1608 + pp;
#pragma unroll
    for (int cg = 0; cg < 2; ++cg) {
      int gq = qn * 2 + cg;
      float4 v;
      if (ok) v = *(const float4*)(src + ((gq * 4 + rot) & 31));
      else    v = make_float4(0.f, 0.f, 0.f, 0.f);
      dst[(cg * 4 + 0) * 200] = v.x;
      dst[(cg * 4 + 1) * 200] = v.y;
      dst[(cg * 4 + 2) * 200] = v.z;
      dst[(cg * 4 + 3) * 200] = v.w;
    }
  };

  __syncthreads();  // imgT ready

  // ---- phase 2: 9 taps x 4 quarter-intervals, pipelined ----
  if (samp) p2sample(0, 0, 0);
  __syncthreads();
  for (int j = 0; j < 9; ++j) {
#pragma unroll
    for (int q = 0; q < 4; ++q) {
      if (samp && !((j == 8) & (q == 3))) {
        int nj = (q == 3) ? j + 1 : j;
        p2sample(nj, (q + 1) & 3, (q + 1) & 1);
      }
      if (oact) {
        const float* sb = Sbuf2 + (q & 1) * 1608 + op0;
#pragma unroll 2
        for (int l = 0; l < 8; ++l) {
          int ci = q * 8 + l;
          float w = ow2t[(ci * 9 + j) * 18 + oc];
          const float* srow = sb + l * 200;
#pragma unroll
          for (int t = 0; t < 4; ++t) {
            float4 s = *(const float4*)(srow + 4 * t);
            oacc[4 * t + 0] = fmaf(w, s.x, oacc[4 * t + 0]);
            oacc[4 * t + 1] = fmaf(w, s.y, oacc[4 * t + 1]);
            oacc[4 * t + 2] = fmaf(w, s.z, oacc[4 * t + 2]);
            oacc[4 * t + 3] = fmaf(w, s.w, oacc[4 * t + 3]);
          }
        }
      }
      __syncthreads();
    }
  }

  // ---- publish tap 0 offsets ----
  if (oact && (oc >> 1) == 0) {
    float* dst = offT + (oc & 1) * 208 + op0;
#pragma unroll
    for (int i = 0; i < 16; ++i) dst[i] = oacc[i] + myob;
  }
  __syncthreads();

  // ---- phase-3 sampler state ----
  float acc[8][8];
  {
    float4 ba = *(const float4*)(b2 + co0);
    float4 bbv = *(const float4*)(b2 + co0 + 4);
    float bj[8] = {ba.x, ba.y, ba.z, ba.w, bbv.x, bbv.y, bbv.z, bbv.w};
#pragma unroll
    for (int jj = 0; jj < 8; ++jj)
#pragma unroll
      for (int i = 0; i < 8; ++i) acc[jj][i] = bj[jj];
  }

  float W00 = 0.f, W01 = 0.f, W10 = 0.f, W11 = 0.f;
  int s00o = 0, s01o = 0, s10o = 0, s11o = 0;
  int r00 = 0, r01 = 0, r10 = 0, r11 = 0;

  auto coeff = [&](int kkv) {
    float dyv = offT[pp];
    float dxv = offT[208 + pp];
    float pyv = (float)(spy - 1 + kkv / 3) + dyv;
    float pxv = (float)(spx - 1 + kkv % 3) + dxv;
    float y0f = floorf(pyv), x0f = floorf(pxv);
    float wy1 = pyv - y0f, wx1 = pxv - x0f;
    float wy0 = 1.f - wy1, wx0 = 1.f - wx1;
    int y0 = (int)y0f, x0 = (int)x0f;
    int y1 = y0 + 1, x1 = x0 + 1;
    bool vy0 = (y0 >= 0) & (y0 < 14), vy1 = (y1 >= 0) & (y1 < 14);
    bool vx0 = (x0 >= 0) & (x0 < 14), vx1 = (x1 >= 0) & (x1 < 14);
    W00 = (vy0 & vx0) ? wy0 * wx0 : 0.f;
    W01 = (vy0 & vx1) ? wy0 * wx1 : 0.f;
    W10 = (vy1 & vx0) ? wy1 * wx0 : 0.f;
    W11 = (vy1 & vx1) ? wy1 * wx1 : 0.f;
    int yc0 = min(max(y0, 0), 13), yc1 = min(max(y1, 0), 13);
    int xc0 = min(max(x0, 0), 13), xc1 = min(max(x1, 0), 13);
    int i00 = yc0 * 14 + xc0, i01 = yc0 * 14 + xc1;
    int i10 = yc1 * 14 + xc0, i11 = yc1 * 14 + xc1;
    s00o = i00 * 32; r00 = (4 * i00) & 31;
    s01o = i01 * 32; r01 = (4 * i01) & 31;
    s10o = i10 * 32; r10 = (4 * i10) & 31;
    s11o = i11 * 32; r11 = (4 * i11) & 31;
  };

  auto sample = [&](int qn, int bufn) {
    float* dst = Sbuf2 + bufn * 1608 + pp;
#pragma unroll
    for (int cg = 0; cg < 2; ++cg) {
      int gq = qn * 2 + cg;
      float4 a0 = *(const float4*)(imgT + s00o + ((gq * 4 + r00) & 31));
      float4 a1 = *(const float4*)(imgT + s01o + ((gq * 4 + r01) & 31));
      float4 a2 = *(const float4*)(imgT + s10o + ((gq * 4 + r10) & 31));
      float4 a3 = *(const float4*)(imgT + s11o + ((gq * 4 + r11) & 31));
      dst[(cg * 4 + 0) * 200] = fmaf(W00, a0.x, fmaf(W01, a1.x, fmaf(W10, a2.x, W11 * a3.x)));
      dst[(cg * 4 + 1) * 200] = fmaf(W00, a0.y, fmaf(W01, a1.y, fmaf(W10, a2.y, W11 * a3.y)));
      dst[(cg * 4 + 2) * 200] = fmaf(W00, a0.z, fmaf(W01, a1.z, fmaf(W10, a2.z, W11 * a3.z)));
      dst[(cg * 4 + 3) * 200] = fmaf(W00, a0.w, fmaf(W01, a1.w, fmaf(W10, a2.w, W11 * a3.w)));
    }
  };

  // ---- phase-3 prologue: tap 0 coeffs + sample quarter 0 into buf 0 ----
  if (samp) { coeff(0); sample(0, 0); }
  __syncthreads();

  // ---- phase 3: 9 taps x 4 quarter-intervals, pipelined ----
  for (int kk = 0; kk < 9; ++kk) {
#pragma unroll
    for (int q = 0; q < 4; ++q) {
      if (samp && !((kk == 8) & (q == 3))) {
        if (q == 3) coeff(kk + 1);  // offT for kk+1 published at (kk, q=2)
        sample((q + 1) & 3, (q + 1) & 1);
      }
      if (gact) {
        const float* sb = Sbuf2 + (q & 1) * 1608 + p0;
        const float* wb = w2t + kk * 64 + co0;
#pragma unroll 2
        for (int l = 0; l < 8; ++l) {
          int ci = q * 8 + l;
          float4 wa = *(const float4*)(wb + ci * 576);
          float4 wbv = *(const float4*)(wb + ci * 576 + 4);
          const float* srow = sb + l * 200;
          float4 s0 = *(const float4*)(srow);
          float4 s1 = *(const float4*)(srow + 4);
          float sv[8] = {s0.x, s0.y, s0.z, s0.w, s1.x, s1.y, s1.z, s1.w};
          float wj[8] = {wa.x, wa.y, wa.z, wa.w, wbv.x, wbv.y, wbv.z, wbv.w};
#pragma unroll
          for (int jj = 0; jj < 8; ++jj)
#pragma unroll
            for (int i = 0; i < 8; ++i)
              acc[jj][i] = fmaf(wj[jj], sv[i], acc[jj][i]);
        }
      }
      // publish offsets for tap kk+1 (consumed at q=3's coeff after the barrier)
      if (q == 2 && kk < 8 && oact && (oc >> 1) == (kk + 1)) {
        float* dst = offT + (oc & 1) * 208 + op0;
#pragma unroll
        for (int i = 0; i < 16; ++i) dst[i] = oacc[i] + myob;
      }
      __syncthreads();
    }
  }

  // ---- epilogue: ReLU + direct float4 global stores ----
  if (gact) {
    float* __restrict__ orow = h2 + b * 12544 + co0 * 196 + p0;
#pragma unroll
    for (int jj = 0; jj < 8; ++jj) {
      float4 v0;
      v0.x = fmaxf(acc[jj][0], 0.f);
      v0.y = fmaxf(acc[jj][1], 0.f);
      v0.z = fmaxf(acc[jj][2], 0.f);
      v0.w = fmaxf(acc[jj][3], 0.f);
      *(float4*)(orow + jj * 196) = v0;
      if (p0 + 4 < 196) {
        float4 v1;
        v1.x = fmaxf(acc[jj][4], 0.f);
        v1.y = fmaxf(acc[jj][5], 0.f);
        v1.z = fmaxf(acc[jj][6], 0.f);
        v1.w = fmaxf(acc[jj][7], 0.f);
        *(float4*)(orow + jj * 196 + 4) = v1;
      }
    }
  }
}

// ---------------- fc1: K-split GEMM 1024x128, K=12544 -> partials[32][1024][128] ----------------
__global__ __launch_bounds__(256, 2) void fc1(const float* __restrict__ h2,
                                              const float* __restrict__ fw1,
                                              float* __restrict__ part) {
  __shared__ float a_s[56 * 72];   // [k][r]
  __shared__ float b_s[56 * 132];  // [k][c]
  int tid = threadIdx.x;
  int rb = (blockIdx.x & 15) * 64;
  int ks = blockIdx.x >> 4;
  int kbase = ks * 392;
  int c0 = (tid & 31) * 4;
  int r0 = (tid >> 5) * 8;

  float acc[8][4];
#pragma unroll
  for (int i = 0; i < 8; ++i)
#pragma unroll
    for (int j = 0; j < 4; ++j) acc[i][j] = 0.f;

  for (int ch = 0; ch < 7; ++ch) {
    int kb = kbase + ch * 56;
    __syncthreads();
#pragma unroll
    for (int t = 0; t < 14; ++t) {
      int idx = t * 256 + tid;
      int r = idx / 56, k = idx - r * 56;
      a_s[k * 72 + r] = h2[(rb + r) * 12544 + kb + k];
    }
#pragma unroll
    for (int t = 0; t < 28; ++t) {
      int idx = t * 256 + tid;
      int c = idx / 56, k = idx - c * 56;
      b_s[k * 132 + c] = fw1[c * 12544 + kb + k];
    }
    __syncthreads();
    for (int k = 0; k < 56; ++k) {
      float4 bv = *(const float4*)&b_s[k * 132 + c0];
      float4 av0 = *(const float4*)&a_s[k * 72 + r0];
      float4 av1 = *(const float4*)&a_s[k * 72 + r0 + 4];
      float av[8] = {av0.x, av0.y, av0.z, av0.w, av1.x, av1.y, av1.z, av1.w};
      float bj[4] = {bv.x, bv.y, bv.z, bv.w};
#pragma unroll
      for (int i = 0; i < 8; ++i)
#pragma unroll
        for (int j = 0; j < 4; ++j) acc[i][j] = fmaf(av[i], bj[j], acc[i][j]);
    }
  }
#pragma unroll
  for (int i = 0; i < 8; ++i) {
    int r = rb + r0 + i;
#pragma unroll
    for (int j = 0; j < 4; ++j)
      part[(ks * 1024 + r) * 128 + c0 + j] = acc[i][j];
  }
}

// ---------------- reduce partials + bias + relu + fc2 ----------------
__global__ __launch_bounds__(128) void fcfinal(const float* __restrict__ part,
                                               const float* __restrict__ fb1,
                                               const float* __restrict__ fw2,
                                               const float* __restrict__ fb2,
                                               float* __restrict__ out) {
  __shared__ float tbuf[128];
  int b = blockIdx.x, c = threadIdx.x;
  float s = fb1[c];
  for (int ks = 0; ks < 32; ++ks) s += part[(ks * 1024 + b) * 128 + c];
  tbuf[c] = fmaxf(s, 0.f);
  __syncthreads();
  if (c < 10) {
    float v = fb2[c];
#pragma unroll
    for (int k = 0; k < 128; ++k) v = fmaf(tbuf[k], fw2[c * 128 + k], v);
    out[b * 10 + c] = v;
  }
}

extern "C" void kernel_launch(void* const* d_in, const int* in_sizes, int n_in,
                              void* d_out, int out_size, void* d_ws, size_t ws_size,
                              hipStream_t stream) {
  const float* x   = (const float*)d_in[0];
  const float* ow1 = (const float*)d_in[1];
  const float* ob1 = (const float*)d_in[2];
  const float* w1  = (const float*)d_in[3];
  const float* b1  = (const float*)d_in[4];
  const float* ow2 = (const float*)d_in[5];
  const float* ob2 = (const float*)d_in[6];
  const float* w2  = (const float*)d_in[7];
  const float* b2  = (const float*)d_in[8];
  const float* fw1 = (const float*)d_in[9];
  const float* fb1 = (const float*)d_in[10];
  const float* fw2 = (const float*)d_in[11];
  const float* fb2 = (const float*)d_in[12];
  float* ws  = (float*)d_ws;
  float* out = (float*)d_out;

  prep<<<72, 256, 0, stream>>>(w1, ow1, w2, ow2, ws);
  stage1<<<784, 256, 0, stream>>>(x, ob1, b1, ws, ws + WS_H1);
  stage2<<<NB, 256, 0, stream>>>(ws + WS_H1, ob2, b2, ws, ws + WS_H2);
  fc1<<<512, 256, 0, stream>>>(ws + WS_H2, fw1, ws + WS_PART);
  fcfinal<<<1024, 128, 0, stream>>>(ws + WS_PART, fb1, fw2, fb2, out);
}